// Round 4
// baseline (508.207 us; speedup 1.0000x reference)
//
#include <hip/hip_runtime.h>
#include <hip/hip_bf16.h>

#define E_ 8
#define H_ 2048
#define I_ 1408
#define S_ 2048       // B*S tokens
#define NPAIR 4096    // S_*K

#define KT1 64        // H_/32  k-steps in gemm1
#define KT2 44        // I_/32  k-steps in gemm2

// convert chunks (2048 floats each)
#define WGBLK 22528   // E_*2*I_*H_/2048
#define WDBLK 11264   // E_*H_*I_/2048
#define XBLK   2048   // S_*H_/2048
#define CVT_BLOCKS 2048

typedef short bf16x8 __attribute__((ext_vector_type(8)));
typedef ushort u16x8 __attribute__((ext_vector_type(8)));
typedef float f32x4  __attribute__((ext_vector_type(4)));

__device__ inline bf16x8 pack8(float4 a, float4 b) {
    bf16x8 r;
    const float v[8] = {a.x, a.y, a.z, a.w, b.x, b.y, b.z, b.w};
#pragma unroll
    for (int j = 0; j < 8; ++j) {
        __hip_bfloat16 t = __float2bfloat16(v[j]);
        r[j] = *reinterpret_cast<short*>(&t);
    }
    return r;
}

// async global->LDS, 16B per lane; LDS dest linear (base + lane*16),
// global source is per-lane (may be strided/gathered)
__device__ __forceinline__ void gload16(const ushort* g, ushort* l) {
    __builtin_amdgcn_global_load_lds(
        (const __attribute__((address_space(1))) void*)g,
        (__attribute__((address_space(3))) void*)l,
        16, 0, 0);
}

// ------------------------------------------- fused convert + router ----
// blocks [0,CVT_BLOCKS): grid-stride fp32->bf16 over wg, wd, x
// block CVT_BLOCKS: router
__global__ __launch_bounds__(256)
void convert_all(const float* __restrict__ wg, const float* __restrict__ wd,
                 const float* __restrict__ x, const int* __restrict__ tki,
                 ushort* __restrict__ wgb, ushort* __restrict__ wdb,
                 ushort* __restrict__ xb,
                 int* __restrict__ counts, int* __restrict__ bases,
                 int* __restrict__ tok, int* __restrict__ inv) {
    const int b = blockIdx.x;
    const int tid = threadIdx.x;
    if (b < CVT_BLOCKS) {
        const int t8 = tid * 8;
        for (int c = b; c < WGBLK; c += CVT_BLOCKS) {
            const size_t i = (size_t)c * 2048 + t8;
            const float4 a = *(const float4*)(wg + i);
            const float4 d = *(const float4*)(wg + i + 4);
            *(bf16x8*)(wgb + i) = pack8(a, d);
        }
        for (int c = b; c < WDBLK; c += CVT_BLOCKS) {
            const size_t i = (size_t)c * 2048 + t8;
            const float4 a = *(const float4*)(wd + i);
            const float4 d = *(const float4*)(wd + i + 4);
            *(bf16x8*)(wdb + i) = pack8(a, d);
        }
        for (int c = b; c < XBLK; c += CVT_BLOCKS) {
            const size_t i = (size_t)c * 2048 + t8;
            const float4 a = *(const float4*)(x + i);
            const float4 d = *(const float4*)(x + i + 4);
            *(bf16x8*)(xb + i) = pack8(a, d);
        }
        return;
    }
    // ------- router (single block) -------
    __shared__ int cnt[E_];
    __shared__ int cur[E_];
    if (tid < E_) cnt[tid] = 0;
    __syncthreads();
    for (int p = tid; p < NPAIR; p += 256)
        atomicAdd(&cnt[tki[p]], 1);
    __syncthreads();
    if (tid == 0) {
        int bb = 0;
        for (int e = 0; e < E_; ++e) {
            counts[e] = cnt[e];
            bases[e]  = bb;
            cur[e]    = bb;
            bb += cnt[e];
        }
    }
    __syncthreads();
    for (int p = tid; p < NPAIR; p += 256) {
        const int e = tki[p];
        const int pos = atomicAdd(&cur[e], 1);
        tok[pos] = p >> 1;   // token id (K=2)
        inv[p]   = pos;      // pair -> sorted position
    }
}

// ------------------------------------------------ GEMM1 (bf16 weights) ----
// grid.y = E_*4; each block loops mt = m0, m0+4, ... (skew-safe, few empties)
__global__ __launch_bounds__(256, 2)
void moe_gemm1(const ushort* __restrict__ xb,
               const ushort* __restrict__ wgb,
               const int* __restrict__ counts,
               const int* __restrict__ bases,
               const int* __restrict__ tok,
               ushort* __restrict__ hbuf) {
    const int e  = blockIdx.y & (E_ - 1);
    const int m0 = blockIdx.y >> 3;          // 0..3
    const int count = counts[e];
    const int base = bases[e];
    const int nt = blockIdx.x;               // 0..10
    const int n0 = nt * 128;
    const ushort* wgbe = wgb + (size_t)e * (2 * I_) * H_;

    // dbuf: 2 x (A,G,U) x 128x32 bf16 = 48 KB; epilogue Ht (34 KB) overlays
    __shared__ alignas(16) ushort sm[24576];

    const int tid  = threadIdx.x;
    const int lane = tid & 63;
    const int wid  = tid >> 6;
    const int wm = wid & 1, wn = wid >> 1;
    const int lr = lane & 15, lq = lane >> 4;

    const int srow = tid >> 2;          // 0..63
    const int sc8  = (tid & 3) * 8;
    const int d0 = tid * 8, d1 = tid * 8 + 2048;
    const f32x4 vzero = {0.f, 0.f, 0.f, 0.f};

    for (int mt = m0; mt * 128 < count; mt += 4) {
        f32x4 accg[4][4], accu[4][4];
#pragma unroll
        for (int mi = 0; mi < 4; ++mi)
#pragma unroll
            for (int ni = 0; ni < 4; ++ni) { accg[mi][ni] = vzero; accu[mi][ni] = vzero; }

        const int ia0 = mt * 128 + srow, ia1 = ia0 + 64;
        const ushort* ap0 = xb + (size_t)(ia0 < count ? tok[base + ia0] : 0) * H_ + sc8;
        const ushort* ap1 = xb + (size_t)(ia1 < count ? tok[base + ia1] : 0) * H_ + sc8;
        const ushort* gp0 = wgbe + (size_t)(n0 + srow) * H_ + sc8;
        const ushort* gp1 = gp0 + (size_t)64 * H_;
        const ushort* up0 = wgbe + (size_t)(I_ + n0 + srow) * H_ + sc8;
        const ushort* up1 = up0 + (size_t)64 * H_;

        // prologue: tile 0 -> buf 0
        {
            ushort* bA = sm; ushort* bG = sm + 4096; ushort* bU = sm + 8192;
            gload16(ap0, bA + d0); gload16(ap1, bA + d1);
            gload16(gp0, bG + d0); gload16(gp1, bG + d1);
            gload16(up0, bU + d0); gload16(up1, bU + d1);
        }

        for (int kt = 0; kt < KT1; ++kt) {
            ushort* curb = sm + (kt & 1) * 12288;
            if (kt + 1 < KT1) {
                ap0 += 32; ap1 += 32; gp0 += 32; gp1 += 32; up0 += 32; up1 += 32;
                ushort* nb = sm + ((kt + 1) & 1) * 12288;
                gload16(ap0, nb + d0);        gload16(ap1, nb + d1);
                gload16(gp0, nb + 4096 + d0); gload16(gp1, nb + 4096 + d1);
                gload16(up0, nb + 8192 + d0); gload16(up1, nb + 8192 + d1);
                asm volatile("s_waitcnt vmcnt(6)" ::: "memory");   // tile kt done
            } else {
                asm volatile("s_waitcnt vmcnt(0)" ::: "memory");
            }
            __builtin_amdgcn_s_barrier();
            __builtin_amdgcn_sched_barrier(0);

            const ushort* As = curb;
            const ushort* Bg = curb + 4096;
            const ushort* Bu = curb + 8192;
            bf16x8 a[4], bg[4], bu[4];
#pragma unroll
            for (int mi = 0; mi < 4; ++mi)
                a[mi] = *(const bf16x8*)&As[(wm * 64 + mi * 16 + lr) * 32 + lq * 8];
#pragma unroll
            for (int ni = 0; ni < 4; ++ni) {
                bg[ni] = *(const bf16x8*)&Bg[(wn * 64 + ni * 16 + lr) * 32 + lq * 8];
                bu[ni] = *(const bf16x8*)&Bu[(wn * 64 + ni * 16 + lr) * 32 + lq * 8];
            }
#pragma unroll
            for (int mi = 0; mi < 4; ++mi)
#pragma unroll
                for (int ni = 0; ni < 4; ++ni) {
                    accg[mi][ni] = __builtin_amdgcn_mfma_f32_16x16x32_bf16(a[mi], bg[ni], accg[mi][ni], 0, 0, 0);
                    accu[mi][ni] = __builtin_amdgcn_mfma_f32_16x16x32_bf16(a[mi], bu[ni], accu[mi][ni], 0, 0, 0);
                }
            __builtin_amdgcn_sched_barrier(0);
            __builtin_amdgcn_s_barrier();
        }

        // epilogue: silu(g)*u -> bf16 tile in LDS (stride 136) -> coalesced stores
        ushort* Ht = sm;
#pragma unroll
        for (int mi = 0; mi < 4; ++mi)
#pragma unroll
            for (int r = 0; r < 4; ++r) {
                const int row = wm * 64 + mi * 16 + lq * 4 + r;
#pragma unroll
                for (int ni = 0; ni < 4; ++ni) {
                    const int col = wn * 64 + ni * 16 + lr;
                    const float g = accg[mi][ni][r];
                    const float u = accu[mi][ni][r];
                    const float h = (g / (1.0f + __expf(-g))) * u;
                    __hip_bfloat16 hb = __float2bfloat16(h);
                    Ht[row * 136 + col] = *reinterpret_cast<ushort*>(&hb);
                }
            }
        __syncthreads();
#pragma unroll
        for (int p = 0; p < 8; ++p) {
            const int slot = p * 256 + tid;
            const int row = slot >> 4;
            const int cc  = (slot & 15) * 8;
            const int gi = mt * 128 + row;
            if (gi < count)
                *(uint4*)&hbuf[(size_t)(base + gi) * I_ + n0 + cc] = *(const uint4*)&Ht[row * 136 + cc];
        }
        __syncthreads();   // LDS reuse guard before next mt iteration
    }
}

// ------------------------------------------------ GEMM2 (bf16 weights) ----
__global__ __launch_bounds__(256, 2)
void moe_gemm2(const ushort* __restrict__ hbuf,
               const ushort* __restrict__ wdb,
               const int* __restrict__ counts,
               const int* __restrict__ bases,
               ushort* __restrict__ ybuf) {
    const int e  = blockIdx.y & (E_ - 1);
    const int m0 = blockIdx.y >> 3;          // 0..3
    const int count = counts[e];
    const int base = bases[e];
    const int nt = blockIdx.x;               // 0..15
    const int n0 = nt * 128;
    const ushort* wdbe = wdb + (size_t)e * H_ * I_;

    // dbuf: 2 x (A,B) x 128x32 = 32 KB; epilogue Yt needs 34 KB -> sm[17408]
    __shared__ alignas(16) ushort sm[17408];

    const int tid  = threadIdx.x;
    const int lane = tid & 63;
    const int wid  = tid >> 6;
    const int wm = wid & 1, wn = wid >> 1;
    const int lr = lane & 15, lq = lane >> 4;

    const int srow = tid >> 2;
    const int sc8  = (tid & 3) * 8;
    const int d0 = tid * 8, d1 = tid * 8 + 2048;
    const f32x4 vzero = {0.f, 0.f, 0.f, 0.f};

    for (int mt = m0; mt * 128 < count; mt += 4) {
        f32x4 acc[4][4];
#pragma unroll
        for (int mi = 0; mi < 4; ++mi)
#pragma unroll
            for (int ni = 0; ni < 4; ++ni) acc[mi][ni] = vzero;

        const int ia0 = mt * 128 + srow, ia1 = ia0 + 64;
        const ushort* ap0 = hbuf + (size_t)(base + (ia0 < count ? ia0 : 0)) * I_ + sc8;
        const ushort* ap1 = hbuf + (size_t)(base + (ia1 < count ? ia1 : 0)) * I_ + sc8;
        const ushort* bp0 = wdbe + (size_t)(n0 + srow) * I_ + sc8;
        const ushort* bp1 = bp0 + (size_t)64 * I_;

        {
            ushort* bA = sm; ushort* bB = sm + 4096;
            gload16(ap0, bA + d0); gload16(ap1, bA + d1);
            gload16(bp0, bB + d0); gload16(bp1, bB + d1);
        }

        for (int kt = 0; kt < KT2; ++kt) {
            ushort* curb = sm + (kt & 1) * 8192;
            if (kt + 1 < KT2) {
                ap0 += 32; ap1 += 32; bp0 += 32; bp1 += 32;
                ushort* nb = sm + ((kt + 1) & 1) * 8192;
                gload16(ap0, nb + d0);        gload16(ap1, nb + d1);
                gload16(bp0, nb + 4096 + d0); gload16(bp1, nb + 4096 + d1);
                asm volatile("s_waitcnt vmcnt(4)" ::: "memory");
            } else {
                asm volatile("s_waitcnt vmcnt(0)" ::: "memory");
            }
            __builtin_amdgcn_s_barrier();
            __builtin_amdgcn_sched_barrier(0);

            const ushort* As = curb;
            const ushort* Bs = curb + 4096;
            bf16x8 a[4], b[4];
#pragma unroll
            for (int mi = 0; mi < 4; ++mi)
                a[mi] = *(const bf16x8*)&As[(wm * 64 + mi * 16 + lr) * 32 + lq * 8];
#pragma unroll
            for (int ni = 0; ni < 4; ++ni)
                b[ni] = *(const bf16x8*)&Bs[(wn * 64 + ni * 16 + lr) * 32 + lq * 8];
#pragma unroll
            for (int mi = 0; mi < 4; ++mi)
#pragma unroll
                for (int ni = 0; ni < 4; ++ni)
                    acc[mi][ni] = __builtin_amdgcn_mfma_f32_16x16x32_bf16(a[mi], b[ni], acc[mi][ni], 0, 0, 0);
            __builtin_amdgcn_sched_barrier(0);
            __builtin_amdgcn_s_barrier();
        }

        ushort* Yt = sm;
#pragma unroll
        for (int mi = 0; mi < 4; ++mi)
#pragma unroll
            for (int r = 0; r < 4; ++r) {
                const int row = wm * 64 + mi * 16 + lq * 4 + r;
#pragma unroll
                for (int ni = 0; ni < 4; ++ni) {
                    const int col = wn * 64 + ni * 16 + lr;
                    __hip_bfloat16 yb = __float2bfloat16(acc[mi][ni][r]);
                    Yt[row * 136 + col] = *reinterpret_cast<ushort*>(&yb);
                }
            }
        __syncthreads();
#pragma unroll
        for (int p = 0; p < 8; ++p) {
            const int slot = p * 256 + tid;
            const int row = slot >> 4;
            const int cc  = (slot & 15) * 8;
            const int gi = mt * 128 + row;
            if (gi < count)
                *(uint4*)&ybuf[(size_t)(base + gi) * H_ + n0 + cc] = *(const uint4*)&Yt[row * 136 + cc];
        }
        __syncthreads();   // LDS reuse guard
    }
}

// --------------------------------------------------------------- combine ----
__global__ void moe_combine(const ushort* __restrict__ ybuf,
                            const int* __restrict__ inv,
                            const float* __restrict__ tkw,
                            float* __restrict__ out) {
    const int t = blockIdx.x;
    const int c8 = threadIdx.x * 8;
    const int p0 = inv[2 * t], p1 = inv[2 * t + 1];
    const float w0 = tkw[2 * t], w1 = tkw[2 * t + 1];
    const u16x8 y0 = *(const u16x8*)(ybuf + (size_t)p0 * H_ + c8);
    const u16x8 y1 = *(const u16x8*)(ybuf + (size_t)p1 * H_ + c8);
    float o[8];
#pragma unroll
    for (int j = 0; j < 8; ++j) {
        const unsigned f0 = ((unsigned)y0[j]) << 16;
        const unsigned f1 = ((unsigned)y1[j]) << 16;
        o[j] = w0 * __uint_as_float(f0) + w1 * __uint_as_float(f1);
    }
    float* dst = out + (size_t)t * H_ + c8;
    *(float4*)dst       = make_float4(o[0], o[1], o[2], o[3]);
    *(float4*)(dst + 4) = make_float4(o[4], o[5], o[6], o[7]);
}

// ---------------------------------------------------------------- launch ----
extern "C" void kernel_launch(void* const* d_in, const int* in_sizes, int n_in,
                              void* d_out, int out_size, void* d_ws, size_t ws_size,
                              hipStream_t stream) {
    const float* x   = (const float*)d_in[0];
    const int*   tki = (const int*)d_in[1];
    const float* tkw = (const float*)d_in[2];
    const float* wg  = (const float*)d_in[3];
    const float* wd  = (const float*)d_in[4];
    float* out = (float*)d_out;

    // ws layout (all 16B-aligned); proven to fit (fast path ran in r2/r3)
    char* p = (char*)d_ws;
    int* counts = (int*)p;  p += 32;
    int* bases  = (int*)p;  p += 32;
    int* tok    = (int*)p;  p += NPAIR * sizeof(int);
    int* inv    = (int*)p;  p += NPAIR * sizeof(int);
    ushort* xb   = (ushort*)p; p += (size_t)S_ * H_ * 2;              // 8 MB
    ushort* hbuf = (ushort*)p; p += (size_t)NPAIR * I_ * 2;           // 11.5 MB
    ushort* ybuf = (ushort*)p; p += (size_t)NPAIR * H_ * 2;           // 16.8 MB
    ushort* wgb  = (ushort*)p; p += (size_t)E_ * (2 * I_) * H_ * 2;   // 92.3 MB (row-major bf16)
    ushort* wdb  = (ushort*)p; p += (size_t)E_ * H_ * I_ * 2;         // 46.1 MB (row-major bf16)

    convert_all<<<dim3(CVT_BLOCKS + 1), 256, 0, stream>>>(
        wg, wd, x, tki, wgb, wdb, xb, counts, bases, tok, inv);
    moe_gemm1<<<dim3(I_ / 128, E_ * 4), 256, 0, stream>>>(xb, wgb, counts, bases, tok, hbuf);
    moe_gemm2<<<dim3(H_ / 128, E_ * 4), 256, 0, stream>>>(hbuf, wdb, counts, bases, ybuf);
    moe_combine<<<dim3(S_), 256, 0, stream>>>(ybuf, inv, tkw, out);
}

// Round 5
// 466.279 us; speedup vs baseline: 1.0899x; 1.0899x over previous
//
#include <hip/hip_runtime.h>
#include <hip/hip_bf16.h>

#define E_ 8
#define H_ 2048
#define I_ 1408
#define S_ 2048       // B*S tokens
#define NPAIR 4096    // S_*K

#define KT1 64        // H_/32  k-steps in gemm1
#define KT2 44        // I_/32  k-steps in gemm2

// convert chunks (2048 floats each)
#define WGBLK 22528   // E_*2*I_*H_/2048  (converted in convert_all)
#define XBLK   2048   // S_*H_/2048       (converted in convert_all)
#define WDBLK 11264   // E_*H_*I_/2048    (converted inside gemm1 blocks)
#define WD_PER_BLK 16 // 704 gemm1 blocks * 16 = 11264

typedef short bf16x8 __attribute__((ext_vector_type(8)));
typedef ushort u16x8 __attribute__((ext_vector_type(8)));
typedef float f32x4  __attribute__((ext_vector_type(4)));

__device__ inline bf16x8 pack8(float4 a, float4 b) {
    bf16x8 r;
    const float v[8] = {a.x, a.y, a.z, a.w, b.x, b.y, b.z, b.w};
#pragma unroll
    for (int j = 0; j < 8; ++j) {
        __hip_bfloat16 t = __float2bfloat16(v[j]);
        r[j] = *reinterpret_cast<short*>(&t);
    }
    return r;
}

// async global->LDS, 16B per lane; LDS dest linear (base + lane*16),
// global source is per-lane
__device__ __forceinline__ void gload16(const ushort* g, ushort* l) {
    __builtin_amdgcn_global_load_lds(
        (const __attribute__((address_space(1))) void*)g,
        (__attribute__((address_space(3))) void*)l,
        16, 0, 0);
}

// ------------------------------------------- convert wg + x, router ----
// blocks [0,WGBLK): wg fp32->bf16, one 2048-float chunk per block
// blocks [WGBLK,WGBLK+XBLK): x
// last block: router
__global__ __launch_bounds__(256)
void convert_all(const float* __restrict__ wg, const float* __restrict__ x,
                 const int* __restrict__ tki,
                 ushort* __restrict__ wgb, ushort* __restrict__ xb,
                 int* __restrict__ counts, int* __restrict__ bases,
                 int* __restrict__ tok, int* __restrict__ inv) {
    const int b = blockIdx.x;
    const int tid = threadIdx.x;
    if (b < WGBLK + XBLK) {
        const float* src;
        ushort* dst;
        size_t off;
        if (b < WGBLK) { src = wg; dst = wgb; off = (size_t)b * 2048; }
        else           { src = x;  dst = xb;  off = (size_t)(b - WGBLK) * 2048; }
        const size_t i = off + (size_t)tid * 8;
        const float4 a = *(const float4*)(src + i);
        const float4 c = *(const float4*)(src + i + 4);
        *(bf16x8*)(dst + i) = pack8(a, c);
        return;
    }
    // ------- router (single block) -------
    __shared__ int cnt[E_];
    __shared__ int cur[E_];
    if (tid < E_) cnt[tid] = 0;
    __syncthreads();
    for (int p = tid; p < NPAIR; p += 256)
        atomicAdd(&cnt[tki[p]], 1);
    __syncthreads();
    if (tid == 0) {
        int bb = 0;
        for (int e = 0; e < E_; ++e) {
            counts[e] = cnt[e];
            bases[e]  = bb;
            cur[e]    = bb;
            bb += cnt[e];
        }
    }
    __syncthreads();
    for (int p = tid; p < NPAIR; p += 256) {
        const int e = tki[p];
        const int pos = atomicAdd(&cur[e], 1);
        tok[pos] = p >> 1;   // token id (K=2)
        inv[p]   = pos;      // pair -> sorted position
    }
}

// ------------------------------------------------ GEMM1 (bf16 weights) ----
// Prologue: each block converts WD_PER_BLK chunks of wd (fp32->bf16) --
// overlapped with the GEMM phase of other blocks; gemm2 (next kernel)
// is the only consumer of wdb. Then: X_gathered @ gate_up[e]^T with
// fused SiLU(gate)*up -> h bf16. dbuf LDS + counted vmcnt.
__global__ __launch_bounds__(256, 2)
void moe_gemm1(const ushort* __restrict__ xb,
               const ushort* __restrict__ wgb,
               const float* __restrict__ wd,
               ushort* __restrict__ wdb,
               const int* __restrict__ counts,
               const int* __restrict__ bases,
               const int* __restrict__ tok,
               ushort* __restrict__ hbuf) {
    const int tid  = threadIdx.x;

    // ---- wd-convert prologue (register-only, no LDS, no barrier) ----
    {
        const int bid = blockIdx.y * gridDim.x + blockIdx.x;   // 0..703
        const size_t t8 = (size_t)tid * 8;
#pragma unroll
        for (int j = 0; j < WD_PER_BLK; ++j) {
            const size_t i = ((size_t)(bid * WD_PER_BLK + j)) * 2048 + t8;
            const float4 a = *(const float4*)(wd + i);
            const float4 c = *(const float4*)(wd + i + 4);
            *(bf16x8*)(wdb + i) = pack8(a, c);
        }
    }

    const int e  = blockIdx.y & (E_ - 1);
    const int m0 = blockIdx.y >> 3;          // 0..7
    const int count = counts[e];
    const int base = bases[e];
    const int nt = blockIdx.x;               // 0..10
    const int n0 = nt * 128;
    const ushort* wgbe = wgb + (size_t)e * (2 * I_) * H_;

    // dbuf: 2 x (A,G,U) x 128x32 bf16 = 48 KB; epilogue Ht (34 KB) overlays
    __shared__ alignas(16) ushort sm[24576];

    const int lane = tid & 63;
    const int wid  = tid >> 6;
    const int wm = wid & 1, wn = wid >> 1;
    const int lr = lane & 15, lq = lane >> 4;

    const int srow = tid >> 2;          // 0..63
    const int sc8  = (tid & 3) * 8;
    const int d0 = tid * 8, d1 = tid * 8 + 2048;
    const f32x4 vzero = {0.f, 0.f, 0.f, 0.f};

    // stride 8 in mt: single pass for count <= 1024 (typical 512); loop is
    // the skew-safety net only.
    for (int mt = m0; mt * 128 < count; mt += 8) {
        f32x4 accg[4][4], accu[4][4];
#pragma unroll
        for (int mi = 0; mi < 4; ++mi)
#pragma unroll
            for (int ni = 0; ni < 4; ++ni) { accg[mi][ni] = vzero; accu[mi][ni] = vzero; }

        const int ia0 = mt * 128 + srow, ia1 = ia0 + 64;
        const ushort* ap0 = xb + (size_t)(ia0 < count ? tok[base + ia0] : 0) * H_ + sc8;
        const ushort* ap1 = xb + (size_t)(ia1 < count ? tok[base + ia1] : 0) * H_ + sc8;
        const ushort* gp0 = wgbe + (size_t)(n0 + srow) * H_ + sc8;
        const ushort* gp1 = gp0 + (size_t)64 * H_;
        const ushort* up0 = wgbe + (size_t)(I_ + n0 + srow) * H_ + sc8;
        const ushort* up1 = up0 + (size_t)64 * H_;

        // prologue: tile 0 -> buf 0
        {
            ushort* bA = sm; ushort* bG = sm + 4096; ushort* bU = sm + 8192;
            gload16(ap0, bA + d0); gload16(ap1, bA + d1);
            gload16(gp0, bG + d0); gload16(gp1, bG + d1);
            gload16(up0, bU + d0); gload16(up1, bU + d1);
        }

        for (int kt = 0; kt < KT1; ++kt) {
            ushort* curb = sm + (kt & 1) * 12288;
            if (kt + 1 < KT1) {
                ap0 += 32; ap1 += 32; gp0 += 32; gp1 += 32; up0 += 32; up1 += 32;
                ushort* nb = sm + ((kt + 1) & 1) * 12288;
                gload16(ap0, nb + d0);        gload16(ap1, nb + d1);
                gload16(gp0, nb + 4096 + d0); gload16(gp1, nb + 4096 + d1);
                gload16(up0, nb + 8192 + d0); gload16(up1, nb + 8192 + d1);
                asm volatile("s_waitcnt vmcnt(6)" ::: "memory");   // tile kt done
            } else {
                asm volatile("s_waitcnt vmcnt(0)" ::: "memory");
            }
            __builtin_amdgcn_s_barrier();
            __builtin_amdgcn_sched_barrier(0);

            const ushort* As = curb;
            const ushort* Bg = curb + 4096;
            const ushort* Bu = curb + 8192;
            bf16x8 a[4], bg[4], bu[4];
#pragma unroll
            for (int mi = 0; mi < 4; ++mi)
                a[mi] = *(const bf16x8*)&As[(wm * 64 + mi * 16 + lr) * 32 + lq * 8];
#pragma unroll
            for (int ni = 0; ni < 4; ++ni) {
                bg[ni] = *(const bf16x8*)&Bg[(wn * 64 + ni * 16 + lr) * 32 + lq * 8];
                bu[ni] = *(const bf16x8*)&Bu[(wn * 64 + ni * 16 + lr) * 32 + lq * 8];
            }
#pragma unroll
            for (int mi = 0; mi < 4; ++mi)
#pragma unroll
                for (int ni = 0; ni < 4; ++ni) {
                    accg[mi][ni] = __builtin_amdgcn_mfma_f32_16x16x32_bf16(a[mi], bg[ni], accg[mi][ni], 0, 0, 0);
                    accu[mi][ni] = __builtin_amdgcn_mfma_f32_16x16x32_bf16(a[mi], bu[ni], accu[mi][ni], 0, 0, 0);
                }
            __builtin_amdgcn_sched_barrier(0);
            __builtin_amdgcn_s_barrier();
        }

        // epilogue: silu(g)*u -> bf16 tile in LDS (stride 136) -> coalesced stores
        ushort* Ht = sm;
#pragma unroll
        for (int mi = 0; mi < 4; ++mi)
#pragma unroll
            for (int r = 0; r < 4; ++r) {
                const int row = wm * 64 + mi * 16 + lq * 4 + r;
#pragma unroll
                for (int ni = 0; ni < 4; ++ni) {
                    const int col = wn * 64 + ni * 16 + lr;
                    const float g = accg[mi][ni][r];
                    const float u = accu[mi][ni][r];
                    const float h = (g / (1.0f + __expf(-g))) * u;
                    __hip_bfloat16 hb = __float2bfloat16(h);
                    Ht[row * 136 + col] = *reinterpret_cast<ushort*>(&hb);
                }
            }
        __syncthreads();
#pragma unroll
        for (int p = 0; p < 8; ++p) {
            const int slot = p * 256 + tid;
            const int row = slot >> 4;
            const int cc  = (slot & 15) * 8;
            const int gi = mt * 128 + row;
            if (gi < count)
                *(uint4*)&hbuf[(size_t)(base + gi) * I_ + n0 + cc] = *(const uint4*)&Ht[row * 136 + cc];
        }
        __syncthreads();   // LDS reuse guard before next mt iteration
    }
}

// ------------------------------------------------ GEMM2 (bf16 weights) ----
__global__ __launch_bounds__(256, 2)
void moe_gemm2(const ushort* __restrict__ hbuf,
               const ushort* __restrict__ wdb,
               const int* __restrict__ counts,
               const int* __restrict__ bases,
               ushort* __restrict__ ybuf) {
    const int e  = blockIdx.y & (E_ - 1);
    const int m0 = blockIdx.y >> 3;          // 0..7
    const int count = counts[e];
    const int base = bases[e];
    const int nt = blockIdx.x;               // 0..15
    const int n0 = nt * 128;
    const ushort* wdbe = wdb + (size_t)e * H_ * I_;

    // dbuf: 2 x (A,B) x 128x32 = 32 KB; epilogue Yt needs 34 KB -> sm[17408]
    __shared__ alignas(16) ushort sm[17408];

    const int tid  = threadIdx.x;
    const int lane = tid & 63;
    const int wid  = tid >> 6;
    const int wm = wid & 1, wn = wid >> 1;
    const int lr = lane & 15, lq = lane >> 4;

    const int srow = tid >> 2;
    const int sc8  = (tid & 3) * 8;
    const int d0 = tid * 8, d1 = tid * 8 + 2048;
    const f32x4 vzero = {0.f, 0.f, 0.f, 0.f};

    for (int mt = m0; mt * 128 < count; mt += 8) {
        f32x4 acc[4][4];
#pragma unroll
        for (int mi = 0; mi < 4; ++mi)
#pragma unroll
            for (int ni = 0; ni < 4; ++ni) acc[mi][ni] = vzero;

        const int ia0 = mt * 128 + srow, ia1 = ia0 + 64;
        const ushort* ap0 = hbuf + (size_t)(base + (ia0 < count ? ia0 : 0)) * I_ + sc8;
        const ushort* ap1 = hbuf + (size_t)(base + (ia1 < count ? ia1 : 0)) * I_ + sc8;
        const ushort* bp0 = wdbe + (size_t)(n0 + srow) * I_ + sc8;
        const ushort* bp1 = bp0 + (size_t)64 * I_;

        {
            ushort* bA = sm; ushort* bB = sm + 4096;
            gload16(ap0, bA + d0); gload16(ap1, bA + d1);
            gload16(bp0, bB + d0); gload16(bp1, bB + d1);
        }

        for (int kt = 0; kt < KT2; ++kt) {
            ushort* curb = sm + (kt & 1) * 8192;
            if (kt + 1 < KT2) {
                ap0 += 32; ap1 += 32; bp0 += 32; bp1 += 32;
                ushort* nb = sm + ((kt + 1) & 1) * 8192;
                gload16(ap0, nb + d0);        gload16(ap1, nb + d1);
                gload16(bp0, nb + 4096 + d0); gload16(bp1, nb + 4096 + d1);
                asm volatile("s_waitcnt vmcnt(4)" ::: "memory");
            } else {
                asm volatile("s_waitcnt vmcnt(0)" ::: "memory");
            }
            __builtin_amdgcn_s_barrier();
            __builtin_amdgcn_sched_barrier(0);

            const ushort* As = curb;
            const ushort* Bs = curb + 4096;
            bf16x8 a[4], b[4];
#pragma unroll
            for (int mi = 0; mi < 4; ++mi)
                a[mi] = *(const bf16x8*)&As[(wm * 64 + mi * 16 + lr) * 32 + lq * 8];
#pragma unroll
            for (int ni = 0; ni < 4; ++ni)
                b[ni] = *(const bf16x8*)&Bs[(wn * 64 + ni * 16 + lr) * 32 + lq * 8];
#pragma unroll
            for (int mi = 0; mi < 4; ++mi)
#pragma unroll
                for (int ni = 0; ni < 4; ++ni)
                    acc[mi][ni] = __builtin_amdgcn_mfma_f32_16x16x32_bf16(a[mi], b[ni], acc[mi][ni], 0, 0, 0);
            __builtin_amdgcn_sched_barrier(0);
            __builtin_amdgcn_s_barrier();
        }

        ushort* Yt = sm;
#pragma unroll
        for (int mi = 0; mi < 4; ++mi)
#pragma unroll
            for (int r = 0; r < 4; ++r) {
                const int row = wm * 64 + mi * 16 + lq * 4 + r;
#pragma unroll
                for (int ni = 0; ni < 4; ++ni) {
                    const int col = wn * 64 + ni * 16 + lr;
                    __hip_bfloat16 yb = __float2bfloat16(acc[mi][ni][r]);
                    Yt[row * 136 + col] = *reinterpret_cast<ushort*>(&yb);
                }
            }
        __syncthreads();
#pragma unroll
        for (int p = 0; p < 8; ++p) {
            const int slot = p * 256 + tid;
            const int row = slot >> 4;
            const int cc  = (slot & 15) * 8;
            const int gi = mt * 128 + row;
            if (gi < count)
                *(uint4*)&ybuf[(size_t)(base + gi) * H_ + n0 + cc] = *(const uint4*)&Yt[row * 136 + cc];
        }
        __syncthreads();   // LDS reuse guard
    }
}

// --------------------------------------------------------------- combine ----
__global__ void moe_combine(const ushort* __restrict__ ybuf,
                            const int* __restrict__ inv,
                            const float* __restrict__ tkw,
                            float* __restrict__ out) {
    const int t = blockIdx.x;
    const int c8 = threadIdx.x * 8;
    const int p0 = inv[2 * t], p1 = inv[2 * t + 1];
    const float w0 = tkw[2 * t], w1 = tkw[2 * t + 1];
    const u16x8 y0 = *(const u16x8*)(ybuf + (size_t)p0 * H_ + c8);
    const u16x8 y1 = *(const u16x8*)(ybuf + (size_t)p1 * H_ + c8);
    float o[8];
#pragma unroll
    for (int j = 0; j < 8; ++j) {
        const unsigned f0 = ((unsigned)y0[j]) << 16;
        const unsigned f1 = ((unsigned)y1[j]) << 16;
        o[j] = w0 * __uint_as_float(f0) + w1 * __uint_as_float(f1);
    }
    float* dst = out + (size_t)t * H_ + c8;
    *(float4*)dst       = make_float4(o[0], o[1], o[2], o[3]);
    *(float4*)(dst + 4) = make_float4(o[4], o[5], o[6], o[7]);
}

// ---------------------------------------------------------------- launch ----
extern "C" void kernel_launch(void* const* d_in, const int* in_sizes, int n_in,
                              void* d_out, int out_size, void* d_ws, size_t ws_size,
                              hipStream_t stream) {
    const float* x   = (const float*)d_in[0];
    const int*   tki = (const int*)d_in[1];
    const float* tkw = (const float*)d_in[2];
    const float* wg  = (const float*)d_in[3];
    const float* wd  = (const float*)d_in[4];
    float* out = (float*)d_out;

    // ws layout (all 16B-aligned); proven to fit (fast path ran r2-r4)
    char* p = (char*)d_ws;
    int* counts = (int*)p;  p += 32;
    int* bases  = (int*)p;  p += 32;
    int* tok    = (int*)p;  p += NPAIR * sizeof(int);
    int* inv    = (int*)p;  p += NPAIR * sizeof(int);
    ushort* xb   = (ushort*)p; p += (size_t)S_ * H_ * 2;              // 8 MB
    ushort* hbuf = (ushort*)p; p += (size_t)NPAIR * I_ * 2;           // 11.5 MB
    ushort* ybuf = (ushort*)p; p += (size_t)NPAIR * H_ * 2;           // 16.8 MB
    ushort* wgb  = (ushort*)p; p += (size_t)E_ * (2 * I_) * H_ * 2;   // 92.3 MB (row-major bf16)
    ushort* wdb  = (ushort*)p; p += (size_t)E_ * H_ * I_ * 2;         // 46.1 MB (row-major bf16)

    convert_all<<<dim3(WGBLK + XBLK + 1), 256, 0, stream>>>(
        wg, x, tki, wgb, xb, counts, bases, tok, inv);
    moe_gemm1<<<dim3(I_ / 128, E_ * 8), 256, 0, stream>>>(
        xb, wgb, wd, wdb, counts, bases, tok, hbuf);
    moe_gemm2<<<dim3(H_ / 128, E_ * 8), 256, 0, stream>>>(hbuf, wdb, counts, bases, ybuf);
    moe_combine<<<dim3(S_), 256, 0, stream>>>(ybuf, inv, tkw, out);
}